// Round 1
// baseline (178.134 us; speedup 1.0000x reference)
//
#include <hip/hip_runtime.h>
#include <cstdint>
#include <cstddef>

#define NB 8
#define NS 2048
#define ND 768
#define NSP 512
#define MAXW 30
#define NH 100
#define SPB 8   // spans per block in kernel 2

// Kernel 1: att_logits[b,s] = dot(seq[b,s,:], att_w) + att_b
// One 64-lane wave per row; float4 loads (768 floats = 192 float4 = 64 lanes x 3).
__global__ __launch_bounds__(256) void att_logits_kernel(
    const float* __restrict__ seq, const float* __restrict__ att_w,
    const float* __restrict__ att_b, float* __restrict__ logits)
{
    int t = threadIdx.x;
    int wave = t >> 6, lane = t & 63;
    int row = blockIdx.x * 4 + wave;              // [0, NB*NS)
    const float4* s4 = (const float4*)(seq + (size_t)row * ND);
    const float4* w4 = (const float4*)att_w;
    float acc = 0.f;
#pragma unroll
    for (int i = 0; i < 3; i++) {
        float4 a = s4[lane + i * 64];
        float4 b = w4[lane + i * 64];
        acc += a.x * b.x + a.y * b.y + a.z * b.z + a.w * b.w;
    }
#pragma unroll
    for (int off = 32; off > 0; off >>= 1) acc += __shfl_down(acc, off);
    if (lane == 0) logits[row] = acc + att_b[0];
}

// Kernel 2: per-span softmax -> attended -> FFNN(tanh)
__global__ __launch_bounds__(256) void span_kernel(
    const float* __restrict__ seq, const int* __restrict__ span_idx,
    const int* __restrict__ span_mask, const float* __restrict__ logits,
    const float* __restrict__ ffnn_w, const float* __restrict__ ffnn_b,
    float* __restrict__ out)
{
    __shared__ float s_attn[SPB][MAXW];
    __shared__ float s_att[SPB][ND + 1];   // +1 pad: adjacent-s same-d -> distinct banks
    __shared__ int   s_start[SPB];
    __shared__ int   s_w[SPB];
    __shared__ float s_mask[SPB];

    int t = threadIdx.x;
    int base = blockIdx.x * SPB;

    // Phase 0: span metadata + masked softmax over span width (threads 0..7)
    if (t < SPB) {
        int gs = base + t;
        int st = span_idx[2 * gs];
        int en = span_idx[2 * gs + 1];     // exclusive end
        int w = en - st;                   // width in [1, MAXW]
        w = max(1, min(w, MAXW));
        s_start[t] = st;
        s_w[t] = w;
        s_mask[t] = (float)span_mask[gs];
        const float* lg = logits + (gs / NSP) * NS + st;
        float mx = -1e30f;
        for (int i = 0; i < w; i++) mx = fmaxf(mx, lg[i]);
        float sum = 0.f;
        for (int i = 0; i < w; i++) {
            float e = expf(lg[i] - mx);
            s_attn[t][i] = e;
            sum += e;
        }
        float inv = 1.f / sum;
        for (int i = 0; i < w; i++) s_attn[t][i] *= inv;
    }
    __syncthreads();

    // Phase 1: attended[s][d] = sum_w attn[w] * seq[b, start+w, d]  (coalesced in d)
    for (int s = 0; s < SPB; s++) {
        int gs = base + s;
        int b = gs / NSP;
        const float* seqb = seq + ((size_t)b * NS + s_start[s]) * ND;
        int w = s_w[s];
        float m = s_mask[s];
#pragma unroll
        for (int r = 0; r < 3; r++) {
            int d = t + r * 256;
            float acc = 0.f;
            for (int i = 0; i < w; i++)
                acc += s_attn[s][i] * seqb[(size_t)i * ND + d];
            s_att[s][d] = acc * m;
        }
    }
    __syncthreads();

    // Phase 2: out[s][h] = tanh(attended[s]·ffnn_w[:,h] + b[h])
    // 200 active threads = 2 span-groups x 100 h; 4 span-accumulators per thread
    // so each ffnn_w element is loaded once per 4 spans.
    if (t < 200) {
        int g = t / 100;
        int h = t - g * 100;
        int s0 = g * 4;
        float bias = ffnn_b[h];
        float acc0 = bias, acc1 = bias, acc2 = bias, acc3 = bias;
        for (int d = 0; d < ND; d++) {
            float wv = ffnn_w[d * NH + h];
            acc0 += s_att[s0 + 0][d] * wv;
            acc1 += s_att[s0 + 1][d] * wv;
            acc2 += s_att[s0 + 2][d] * wv;
            acc3 += s_att[s0 + 3][d] * wv;
        }
        size_t o = (size_t)(base + s0) * NH + h;
        out[o]          = tanhf(acc0);
        out[o + NH]     = tanhf(acc1);
        out[o + 2 * NH] = tanhf(acc2);
        out[o + 3 * NH] = tanhf(acc3);
    }
}

extern "C" void kernel_launch(void* const* d_in, const int* in_sizes, int n_in,
                              void* d_out, int out_size, void* d_ws, size_t ws_size,
                              hipStream_t stream) {
    const float* seq      = (const float*)d_in[0];  // [B,S,D]
    const int*   span_idx = (const int*)d_in[1];    // [B,N,2] (int32 on device)
    const int*   span_msk = (const int*)d_in[2];    // [B,N]
    const float* att_w    = (const float*)d_in[3];  // [D,1]
    const float* att_b    = (const float*)d_in[4];  // [1]
    const float* ffnn_w   = (const float*)d_in[5];  // [D,H]
    const float* ffnn_b   = (const float*)d_in[6];  // [H]
    float* out = (float*)d_out;                     // [B,N,H]
    float* logits = (float*)d_ws;                   // B*S floats = 64 KB

    // Kernel 1: 16384 rows, 4 waves/block -> 4096 blocks
    att_logits_kernel<<<(NB * NS) / 4, 256, 0, stream>>>(seq, att_w, att_b, logits);

    // Kernel 2: 4096 spans / 8 per block -> 512 blocks
    span_kernel<<<(NB * NSP) / SPB, 256, 0, stream>>>(
        seq, span_idx, span_msk, logits, ffnn_w, ffnn_b, out);
}